// Round 1
// baseline (105.330 us; speedup 1.0000x reference)
//
#include <hip/hip_runtime.h>
#include <math.h>

// Problem constants (fixed shapes from reference)
#define KNUM 256
#define HH 62
#define WW 64
#define BB 768            // N*C = 4*192
#define JV 1024           // vectors per plane = W*Hp/D = 64*64/4
#define M_TOT (BB*JV)     // 786432
#define QL_SIZE (BB*HH*WW) // 3047424

// d_out layout (concatenated tuple, float32):
// [0, QL_SIZE)            ql
// [QL_SIZE]               mse_loss
// [QL_SIZE+1, +M_TOT)     inds (as float)
// [OFF_RATE]              rate_uem
// [OFF_RATE+1]            prior_dist (0)
// [OFF_RATE+2]            param_bit (0)
#define OFF_MSE   QL_SIZE
#define OFF_INDS  (QL_SIZE + 1)
#define OFF_RATE  (OFF_INDS + M_TOT)

#define XT_STRIDE 68   // 68*4B = 272B = 17*16B -> float4-aligned rows, banks spread

__global__ void vq_init_out(float* __restrict__ out) {
    int t = threadIdx.x;
    if (t == 0) out[OFF_MSE] = 0.0f;
    else if (t == 1) out[OFF_RATE] = 0.0f;
    else if (t == 2) out[OFF_RATE + 1] = 0.0f;
    else if (t == 3) out[OFF_RATE + 2] = 0.0f;
}

__launch_bounds__(256)
__global__ void vq_main(const float* __restrict__ latents,
                        const float* __restrict__ codebook,
                        const float* __restrict__ log_pmf,
                        float* __restrict__ out) {
    __shared__ float xt[64 * XT_STRIDE];   // transposed plane [w][h], 17.4 KB
    __shared__ float4 cbv[KNUM];           // codebook rows
    __shared__ float  cck[KNUM];           // ||c||^2 + rate_bias
    __shared__ float  l2v[KNUM];           // log2_pmf
    __shared__ float  wred[8];

    const int t = threadIdx.x;
    const int b = blockIdx.x;
    const float* lat = latents + (size_t)b * (HH * WW);

    // ---- stage codebook tables (256 threads == 256 entries) ----
    {
        float4 c = ((const float4*)codebook)[t];
        float lp = log_pmf[t];
        float l2 = lp * (-1.44269504088896340736f);   // log_pmf / (-ln 2)
        l2v[t] = l2;
        cck[t] = c.x * c.x + c.y * c.y + c.z * c.z + c.w * c.w + l2 * 100.0f; // /LMBDA
        cbv[t] = c;
    }

    // ---- stage latents plane transposed into LDS (with pad rows 62,63 = rows 60,61) ----
    for (int idx = t; idx < (HH * WW / 4); idx += 256) {
        int h  = idx >> 4;     // row 0..61
        int wq = idx & 15;     // float4 column
        float4 v = ((const float4*)lat)[idx];
        int w0 = wq * 4;
        xt[(w0 + 0) * XT_STRIDE + h] = v.x;
        xt[(w0 + 1) * XT_STRIDE + h] = v.y;
        xt[(w0 + 2) * XT_STRIDE + h] = v.z;
        xt[(w0 + 3) * XT_STRIDE + h] = v.w;
        if (h >= 60) {     // replicate rows 60,61 -> 62,63
            int h2 = h + 2;
            xt[(w0 + 0) * XT_STRIDE + h2] = v.x;
            xt[(w0 + 1) * XT_STRIDE + h2] = v.y;
            xt[(w0 + 2) * XT_STRIDE + h2] = v.z;
            xt[(w0 + 3) * XT_STRIDE + h2] = v.w;
        }
    }
    __syncthreads();

    // ---- per-thread: 4 vectors j = t + 256*i ----
    float4 y[4];
    float  dmin[4];
    int    kmin[4];
#pragma unroll
    for (int i = 0; i < 4; ++i) {
        int j  = t + 256 * i;
        int w  = j >> 4;
        int hc = j & 15;
        float4 x = *(const float4*)&xt[w * XT_STRIDE + hc * 4];
        y[i].x = -2.0f * x.x;
        y[i].y = -2.0f * x.y;
        y[i].z = -2.0f * x.z;
        y[i].w = -2.0f * x.w;
        dmin[i] = INFINITY;
        kmin[i] = 0;
    }

    // ---- argmin over 256 codewords; dist = ||c||^2 + bias + y.c  (y = -2x) ----
#pragma unroll 4
    for (int k = 0; k < KNUM; k += 2) {
        float4 ca = cbv[k];
        float  qa = cck[k];
        float4 cb = cbv[k + 1];
        float  qb = cck[k + 1];
#pragma unroll
        for (int i = 0; i < 4; ++i) {
            float d0 = fmaf(y[i].x, ca.x, qa);
            d0 = fmaf(y[i].y, ca.y, d0);
            d0 = fmaf(y[i].z, ca.z, d0);
            d0 = fmaf(y[i].w, ca.w, d0);
            float d1 = fmaf(y[i].x, cb.x, qb);
            d1 = fmaf(y[i].y, cb.y, d1);
            d1 = fmaf(y[i].z, cb.z, d1);
            d1 = fmaf(y[i].w, cb.w, d1);
            // first-occurrence-wins tie-breaking (strict <), matches np.argmin
            bool  s1 = d1 < d0;
            float dp = s1 ? d1 : d0;
            int   kp = s1 ? (k + 1) : k;
            bool  sg = dp < dmin[i];
            dmin[i] = sg ? dp : dmin[i];
            kmin[i] = sg ? kp : kmin[i];
        }
    }

    // ---- epilogue per vector: gather q, accumulate mse/rate, write q in place, write ind ----
    float mse_acc = 0.0f;
    float rate_acc = 0.0f;
#pragma unroll
    for (int i = 0; i < 4; ++i) {
        int j  = t + 256 * i;
        int w  = j >> 4;
        int hc = j & 15;
        float4 c = cbv[kmin[i]];
        rate_acc += l2v[kmin[i]];
        float e0 = fmaf(0.5f, y[i].x, c.x);   // c - x
        float e1 = fmaf(0.5f, y[i].y, c.y);
        float e2 = fmaf(0.5f, y[i].z, c.z);
        float e3 = fmaf(0.5f, y[i].w, c.w);
        mse_acc += e0 * e0 + e1 * e1 + e2 * e2 + e3 * e3;
        *(float4*)&xt[w * XT_STRIDE + hc * 4] = c;   // overwrite x with q (slot private to this vector)
        out[OFF_INDS + (size_t)b * JV + j] = (float)kmin[i];
    }
    __syncthreads();

    // ---- coalesced crop/transpose write-out: ql[b, h, w] = xt[w][h], h < 62 ----
    for (int idx = t; idx < HH * WW; idx += 256) {
        int h = idx >> 6;
        int w = idx & 63;
        out[(size_t)b * (HH * WW) + idx] = xt[w * XT_STRIDE + h];
    }

    // ---- block reduction of mse/rate -> one atomicAdd each ----
#pragma unroll
    for (int off = 32; off > 0; off >>= 1) {
        mse_acc  += __shfl_down(mse_acc, off, 64);
        rate_acc += __shfl_down(rate_acc, off, 64);
    }
    int wave = t >> 6, lane = t & 63;
    if (lane == 0) { wred[wave] = mse_acc; wred[4 + wave] = rate_acc; }
    __syncthreads();
    if (t == 0) {
        float m = wred[0] + wred[1] + wred[2] + wred[3];
        float r = wred[4] + wred[5] + wred[6] + wred[7];
        atomicAdd(&out[OFF_MSE], m * (1.0f / 3145728.0f));  // mean over B*JV*D
        atomicAdd(&out[OFF_RATE], r);
    }
}

extern "C" void kernel_launch(void* const* d_in, const int* in_sizes, int n_in,
                              void* d_out, int out_size, void* d_ws, size_t ws_size,
                              hipStream_t stream) {
    const float* latents  = (const float*)d_in[0];
    const float* codebook = (const float*)d_in[1];
    const float* log_pmf  = (const float*)d_in[2];
    float* out = (float*)d_out;

    vq_init_out<<<1, 64, 0, stream>>>(out);
    vq_main<<<BB, 256, 0, stream>>>(latents, codebook, log_pmf, out);
}